// Round 1
// baseline (711.592 us; speedup 1.0000x reference)
//
#include <hip/hip_runtime.h>
#include <cstdint>

#define THREADS 256

// ---------------- init ----------------
__global__ void init_kernel(int* deg, float* pool, int* root, int N, int G) {
  int i = blockIdx.x * blockDim.x + threadIdx.x;
  if (i < N) deg[i] = 0;
  if (i < G * 64) pool[i] = 0.0f;
  if (i < G) root[i] = 0x7fffffff;
}

// ---------------- CSR build ----------------
__global__ void deg_kernel(const int* __restrict__ dst_e, int* __restrict__ deg,
                           int E, int Etot) {
  int i = blockIdx.x * blockDim.x + threadIdx.x;
  if (i >= Etot) return;
  int d = (i < E) ? dst_e[i] : (i - E);
  atomicAdd(&deg[d], 1);
}

// block scans 1024 elements (256 threads x 4)
__global__ void scan1_kernel(const int* __restrict__ deg, int* __restrict__ row1,
                             int* __restrict__ bsum, int N) {
  __shared__ int tsum[256];
  int t = threadIdx.x, b = blockIdx.x;
  int base = b * 1024 + t * 4;
  int v[4];
  int run = 0;
  for (int j = 0; j < 4; j++) {
    int idx = base + j;
    int d = (idx < N) ? deg[idx] : 0;
    run += d;
    v[j] = run;
  }
  tsum[t] = run;
  __syncthreads();
  int own = run;
  for (int off = 1; off < 256; off <<= 1) {
    int val = (t >= off) ? tsum[t - off] : 0;
    __syncthreads();
    tsum[t] += val;
    __syncthreads();
  }
  int prefix = tsum[t] - own;
  for (int j = 0; j < 4; j++) {
    int idx = base + j;
    if (idx < N) row1[idx] = prefix + v[j];  // inclusive scan -> row_start[idx+1]
  }
  if (t == 255) bsum[b] = tsum[255];
}

__global__ void scan2_kernel(const int* __restrict__ bsum, int* __restrict__ boff, int NB) {
  __shared__ int s[256];
  int t = threadIdx.x;
  int v = (t < NB) ? bsum[t] : 0;
  s[t] = v;
  __syncthreads();
  int own = v;
  for (int off = 1; off < 256; off <<= 1) {
    int val = (t >= off) ? s[t - off] : 0;
    __syncthreads();
    s[t] += val;
    __syncthreads();
  }
  if (t < NB) boff[t] = s[t] - own;  // exclusive
}

__global__ void scan3_kernel(int* __restrict__ row_start, int* __restrict__ cursor,
                             const int* __restrict__ boff, int N) {
  int i = blockIdx.x * blockDim.x + threadIdx.x;
  if (i >= N) return;
  int val = row_start[i + 1] + boff[i >> 10];
  row_start[i + 1] = val;
  if (i + 1 < N) cursor[i + 1] = val;
  if (i == 0) { row_start[0] = 0; cursor[0] = 0; }
}

__global__ void fill_kernel(const int* __restrict__ src_e, const int* __restrict__ dst_e,
                            int* __restrict__ cursor, int* __restrict__ csr_src,
                            int E, int Etot) {
  int i = blockIdx.x * blockDim.x + threadIdx.x;
  if (i >= Etot) return;
  int s, d;
  if (i < E) { s = src_e[i]; d = dst_e[i]; }
  else       { s = i - E;    d = i - E;    }
  int slot = atomicAdd(&cursor[d], 1);
  csr_src[slot] = s;
}

// ---------------- linear + attention scalars ----------------
// h = in @ W  [N,64]; as_[n] = h[n].a_src; ad_[n] = h[n].a_dst
// wave handles 8 nodes; thread = (nl = lane>>4 -> nodes nl, nl+4; cg = lane&15 -> ch 4*cg..4*cg+3)
template <int K>
__global__ __launch_bounds__(256) void lin_attn_kernel(
    const float* __restrict__ in, const float* __restrict__ W,
    const float* __restrict__ a_src, const float* __restrict__ a_dst,
    float* __restrict__ h, float* __restrict__ as_, float* __restrict__ ad_, int N) {
  constexpr int KP = K + 4;
  __shared__ float sW[K * 64];
  __shared__ float sIn[4][8][KP];
  const int t = threadIdx.x;
  const int lane = t & 63, w = t >> 6;
  const int cg = lane & 15, nl = lane >> 4;

  for (int i = t; i < K * 64; i += 256) sW[i] = W[i];

  const int nodeBase = blockIdx.x * 32 + w * 8;
  {
    const int nf4 = 8 * (K / 4);
    const float4* inv4 = (const float4*)(in + (size_t)nodeBase * K);
    for (int i = lane; i < nf4; i += 64) {
      int row = i / (K / 4), j = i % (K / 4);
      if (nodeBase + row < N) {
        float4 v = inv4[i];
        *(float4*)&sIn[w][row][j * 4] = v;
      }
    }
  }
  __syncthreads();

  float acc[2][4] = {{0.f, 0.f, 0.f, 0.f}, {0.f, 0.f, 0.f, 0.f}};
#pragma unroll 8
  for (int k = 0; k < K; k++) {
    float4 wv = *(const float4*)&sW[k * 64 + cg * 4];
    float i0 = sIn[w][nl][k];
    float i1 = sIn[w][nl + 4][k];
    acc[0][0] += i0 * wv.x; acc[0][1] += i0 * wv.y;
    acc[0][2] += i0 * wv.z; acc[0][3] += i0 * wv.w;
    acc[1][0] += i1 * wv.x; acc[1][1] += i1 * wv.y;
    acc[1][2] += i1 * wv.z; acc[1][3] += i1 * wv.w;
  }

  float4 av = *(const float4*)(a_src + cg * 4);
  float4 dv = *(const float4*)(a_dst + cg * 4);
#pragma unroll
  for (int p = 0; p < 2; p++) {
    int n = nodeBase + nl + p * 4;
    if (n < N) {
      float4 hv = make_float4(acc[p][0], acc[p][1], acc[p][2], acc[p][3]);
      *(float4*)(h + (size_t)n * 64 + cg * 4) = hv;
      float ps = acc[p][0] * av.x + acc[p][1] * av.y + acc[p][2] * av.z + acc[p][3] * av.w;
      float pd = acc[p][0] * dv.x + acc[p][1] * dv.y + acc[p][2] * dv.z + acc[p][3] * dv.w;
      for (int m = 1; m < 16; m <<= 1) {
        ps += __shfl_xor(ps, m);
        pd += __shfl_xor(pd, m);
      }
      if (cg == 0) { as_[n] = ps; ad_[n] = pd; }
    }
  }
}

// ---------------- edge softmax coefficients (16 lanes per node) ----------------
__global__ void coef_kernel(const float* __restrict__ as_, const float* __restrict__ ad_,
                            const int* __restrict__ csr_src, const int* __restrict__ row_start,
                            float* __restrict__ coef, int N) {
  int gt = blockIdx.x * blockDim.x + threadIdx.x;
  int node = gt >> 4;
  int l = gt & 15;
  if (node >= N) return;
  int rs = row_start[node], re = row_start[node + 1];
  float adn = ad_[node];
  float m = -3.4e38f;
  for (int s = rs + l; s < re; s += 16) {
    float e = as_[csr_src[s]] + adn;
    e = (e > 0.f) ? e : 0.2f * e;  // leaky_relu 0.2
    coef[s] = e;
    m = fmaxf(m, e);
  }
  for (int k = 1; k < 16; k <<= 1) m = fmaxf(m, __shfl_xor(m, k));
  float sum = 0.f;
  for (int s = rs + l; s < re; s += 16) {
    float num = __expf(coef[s] - m);
    coef[s] = num;
    sum += num;
  }
  for (int k = 1; k < 16; k <<= 1) sum += __shfl_xor(sum, k);
  float inv = 1.0f / (sum + 1e-16f);
  for (int s = rs + l; s < re; s += 16) coef[s] *= inv;
}

// ---------------- aggregation: out[n] = relu(sum coef*h[src] + b) ----------------
__global__ __launch_bounds__(256) void agg_kernel(
    const float* __restrict__ h, const float* __restrict__ coef,
    const int* __restrict__ csr_src, const int* __restrict__ row_start,
    const float* __restrict__ b, float* __restrict__ out, int N) {
  int t = threadIdx.x;
  int lane = t & 63, w = t >> 6;
  int n = blockIdx.x * 4 + w;
  if (n >= N) return;
  int rs = row_start[n], re = row_start[n + 1];
  float acc = 0.f;
  for (int s = rs; s < re; s++) {
    int src = csr_src[s];
    float cf = coef[s];
    acc += cf * h[(size_t)src * 64 + lane];
  }
  out[(size_t)n * 64 + lane] = fmaxf(acc + b[lane], 0.0f);
}

// ---------------- global max pool + root detection ----------------
__global__ void pool_kernel(const float* __restrict__ h, const int* __restrict__ batch,
                            float* __restrict__ pool, int* __restrict__ root,
                            int N, int chunk) {
  int t = threadIdx.x;
  int lane = t & 63, w = t >> 6;
  int row = blockIdx.x * 4 + w;
  int start = row * chunk;
  if (start >= N) return;
  int end = start + chunk; if (end > N) end = N;
  int cur_g = batch[start];
  if (lane == 0 && (start == 0 || batch[start - 1] != cur_g)) atomicMin(&root[cur_g], start);
  float rm = 0.0f;  // h >= 0 (post-relu), pool init 0
  for (int n = start; n < end; n++) {
    int g = batch[n];
    if (g != cur_g) {
      atomicMax((int*)&pool[(size_t)cur_g * 64 + lane], __float_as_int(rm));
      if (lane == 0) atomicMin(&root[g], n);
      cur_g = g;
      rm = 0.0f;
    }
    rm = fmaxf(rm, h[(size_t)n * 64 + lane]);
  }
  atomicMax((int*)&pool[(size_t)cur_g * 64 + lane], __float_as_int(rm));
}

// ---------------- final fused MLP head (wave per graph) ----------------
__global__ void final_kernel(const float* __restrict__ pool, const int* __restrict__ root,
                             const float* __restrict__ x,
                             const float* __restrict__ lin0_W, const float* __restrict__ lin0_b,
                             const float* __restrict__ linnews_W, const float* __restrict__ linnews_b,
                             const float* __restrict__ lin1_W, const float* __restrict__ lin1_b,
                             float* __restrict__ out, int G, int N) {
  int t = threadIdx.x;
  int lane = t & 63, w = t >> 6;
  int g = blockIdx.x * 4 + w;
  if (g >= G) return;
  float hp = 0.f;
  for (int k = 0; k < 64; k++) hp += pool[(size_t)g * 64 + k] * lin0_W[k * 64 + lane];
  hp = fmaxf(hp + lin0_b[lane], 0.f);
  int r = root[g]; if (r > N - 1) r = N - 1; if (r < 0) r = 0;
  float nw = 0.f;
  for (int k = 0; k < 128; k++) nw += x[(size_t)r * 128 + k] * linnews_W[k * 64 + lane];
  nw = fmaxf(nw + linnews_b[lane], 0.f);
  float p = hp * lin1_W[lane] + nw * lin1_W[64 + lane];
  for (int k = 1; k < 64; k <<= 1) p += __shfl_xor(p, k);
  if (lane == 0) out[g] = 1.0f / (1.0f + __expf(-(p + lin1_b[0])));
}

// ---------------- launch ----------------
extern "C" void kernel_launch(void* const* d_in, const int* in_sizes, int n_in,
                              void* d_out, int out_size, void* d_ws, size_t ws_size,
                              hipStream_t stream) {
  (void)n_in; (void)ws_size;
  const float* x      = (const float*)d_in[0];
  const int*   adj    = (const int*)d_in[1];
  const int*   batch  = (const int*)d_in[2];
  const float* W1     = (const float*)d_in[3];
  const float* asrc1  = (const float*)d_in[4];
  const float* adst1  = (const float*)d_in[5];
  const float* b1     = (const float*)d_in[6];
  const float* W2     = (const float*)d_in[7];
  const float* asrc2  = (const float*)d_in[8];
  const float* adst2  = (const float*)d_in[9];
  const float* b2     = (const float*)d_in[10];
  const float* W3     = (const float*)d_in[11];
  const float* asrc3  = (const float*)d_in[12];
  const float* adst3  = (const float*)d_in[13];
  const float* b3     = (const float*)d_in[14];
  const float* lnW    = (const float*)d_in[15];
  const float* lnb    = (const float*)d_in[16];
  const float* l0W    = (const float*)d_in[17];
  const float* l0b    = (const float*)d_in[18];
  const float* l1W    = (const float*)d_in[19];
  const float* l1b    = (const float*)d_in[20];
  float* outp = (float*)d_out;

  const int N = in_sizes[2];
  const int E = in_sizes[1] / 2;
  const int Etot = E + N;
  const int G = out_size;

  const int* src_e = adj;
  const int* dst_e = adj + E;

  uintptr_t p = (uintptr_t)d_ws;
  auto alloc = [&](size_t bytes) -> void* {
    void* r = (void*)p;
    p += (bytes + 255) & ~(size_t)255;
    return r;
  };
  int*   deg       = (int*)alloc((size_t)N * 4);
  int*   row_start = (int*)alloc((size_t)(N + 1) * 4);
  int*   cursor    = (int*)alloc((size_t)N * 4);
  int*   bsum      = (int*)alloc(1024);
  int*   boff      = (int*)alloc(1024);
  int*   csr_src   = (int*)alloc((size_t)Etot * 4);
  float* coef      = (float*)alloc((size_t)Etot * 4);
  float* h_lin     = (float*)alloc((size_t)N * 64 * 4);
  float* bufA      = (float*)alloc((size_t)N * 64 * 4);
  float* as_       = (float*)alloc((size_t)N * 4);
  float* ad_       = (float*)alloc((size_t)N * 4);
  float* pool      = (float*)alloc((size_t)G * 64 * 4);
  int*   root      = (int*)alloc((size_t)G * 4);

  int initN = (N > G * 64) ? N : G * 64;
  init_kernel<<<dim3((initN + THREADS - 1) / THREADS), dim3(THREADS), 0, stream>>>(deg, pool, root, N, G);

  int egrid = (Etot + THREADS - 1) / THREADS;
  deg_kernel<<<dim3(egrid), dim3(THREADS), 0, stream>>>(dst_e, deg, E, Etot);

  int NB = (N + 1023) / 1024;
  scan1_kernel<<<dim3(NB), dim3(256), 0, stream>>>(deg, row_start + 1, bsum, N);
  scan2_kernel<<<dim3(1), dim3(256), 0, stream>>>(bsum, boff, NB);
  scan3_kernel<<<dim3((N + THREADS - 1) / THREADS), dim3(THREADS), 0, stream>>>(row_start, cursor, boff, N);
  fill_kernel<<<dim3(egrid), dim3(THREADS), 0, stream>>>(src_e, dst_e, cursor, csr_src, E, Etot);

  const int linGrid = (N + 31) / 32;
  const int coefGrid = (int)(((size_t)N * 16 + 255) / 256);
  const int aggGrid = (N + 3) / 4;

  // layer 1
  lin_attn_kernel<128><<<dim3(linGrid), dim3(256), 0, stream>>>(x, W1, asrc1, adst1, h_lin, as_, ad_, N);
  coef_kernel<<<dim3(coefGrid), dim3(256), 0, stream>>>(as_, ad_, csr_src, row_start, coef, N);
  agg_kernel<<<dim3(aggGrid), dim3(256), 0, stream>>>(h_lin, coef, csr_src, row_start, b1, bufA, N);
  // layer 2
  lin_attn_kernel<64><<<dim3(linGrid), dim3(256), 0, stream>>>(bufA, W2, asrc2, adst2, h_lin, as_, ad_, N);
  coef_kernel<<<dim3(coefGrid), dim3(256), 0, stream>>>(as_, ad_, csr_src, row_start, coef, N);
  agg_kernel<<<dim3(aggGrid), dim3(256), 0, stream>>>(h_lin, coef, csr_src, row_start, b2, bufA, N);
  // layer 3
  lin_attn_kernel<64><<<dim3(linGrid), dim3(256), 0, stream>>>(bufA, W3, asrc3, adst3, h_lin, as_, ad_, N);
  coef_kernel<<<dim3(coefGrid), dim3(256), 0, stream>>>(as_, ad_, csr_src, row_start, coef, N);
  agg_kernel<<<dim3(aggGrid), dim3(256), 0, stream>>>(h_lin, coef, csr_src, row_start, b3, bufA, N);

  // pool + root
  const int ROWS = 2048;
  int chunk = (N + ROWS - 1) / ROWS;
  pool_kernel<<<dim3(ROWS / 4), dim3(256), 0, stream>>>(bufA, batch, pool, root, N, chunk);

  // head
  final_kernel<<<dim3((G + 3) / 4), dim3(256), 0, stream>>>(
      pool, root, x, l0W, l0b, lnW, lnb, l1W, l1b, outp, G, N);
}

// Round 2
// 531.461 us; speedup vs baseline: 1.3389x; 1.3389x over previous
//
#include <hip/hip_runtime.h>
#include <cstdint>

#define THREADS 256

// ---------------- init ----------------
__global__ void init_kernel(int* deg, float* pool, int* root, int N, int G) {
  int i = blockIdx.x * blockDim.x + threadIdx.x;
  if (i < N) deg[i] = 0;
  if (i < G * 64) pool[i] = 0.0f;
  if (i < G) root[i] = 0x7fffffff;
}

// ---------------- CSR build ----------------
__global__ void deg_kernel(const int* __restrict__ dst_e, int* __restrict__ deg,
                           int E, int Etot) {
  int i = blockIdx.x * blockDim.x + threadIdx.x;
  if (i >= Etot) return;
  int d = (i < E) ? dst_e[i] : (i - E);
  atomicAdd(&deg[d], 1);
}

// block scans 1024 elements (256 threads x 4)
__global__ void scan1_kernel(const int* __restrict__ deg, int* __restrict__ row1,
                             int* __restrict__ bsum, int N) {
  __shared__ int tsum[256];
  int t = threadIdx.x, b = blockIdx.x;
  int base = b * 1024 + t * 4;
  int v[4];
  int run = 0;
  for (int j = 0; j < 4; j++) {
    int idx = base + j;
    int d = (idx < N) ? deg[idx] : 0;
    run += d;
    v[j] = run;
  }
  tsum[t] = run;
  __syncthreads();
  int own = run;
  for (int off = 1; off < 256; off <<= 1) {
    int val = (t >= off) ? tsum[t - off] : 0;
    __syncthreads();
    tsum[t] += val;
    __syncthreads();
  }
  int prefix = tsum[t] - own;
  for (int j = 0; j < 4; j++) {
    int idx = base + j;
    if (idx < N) row1[idx] = prefix + v[j];  // inclusive scan -> row_start[idx+1]
  }
  if (t == 255) bsum[b] = tsum[255];
}

__global__ void scan2_kernel(const int* __restrict__ bsum, int* __restrict__ boff, int NB) {
  __shared__ int s[256];
  int t = threadIdx.x;
  int v = (t < NB) ? bsum[t] : 0;
  s[t] = v;
  __syncthreads();
  int own = v;
  for (int off = 1; off < 256; off <<= 1) {
    int val = (t >= off) ? s[t - off] : 0;
    __syncthreads();
    s[t] += val;
    __syncthreads();
  }
  if (t < NB) boff[t] = s[t] - own;  // exclusive
}

__global__ void scan3_kernel(int* __restrict__ row_start, int* __restrict__ cursor,
                             const int* __restrict__ boff, int N) {
  int i = blockIdx.x * blockDim.x + threadIdx.x;
  if (i >= N) return;
  int val = row_start[i + 1] + boff[i >> 10];
  row_start[i + 1] = val;
  if (i + 1 < N) cursor[i + 1] = val;
  if (i == 0) { row_start[0] = 0; cursor[0] = 0; }
}

__global__ void fill_kernel(const int* __restrict__ src_e, const int* __restrict__ dst_e,
                            int* __restrict__ cursor, int* __restrict__ csr_src,
                            int E, int Etot) {
  int i = blockIdx.x * blockDim.x + threadIdx.x;
  if (i >= Etot) return;
  int s, d;
  if (i < E) { s = src_e[i]; d = dst_e[i]; }
  else       { s = i - E;    d = i - E;    }
  int slot = atomicAdd(&cursor[d], 1);
  csr_src[slot] = s;
}

// ---------------- linear + attention scalars ----------------
// h = in @ W  [N,64]; as_[n] = h[n].a_src; ad_[n] = h[n].a_dst
// wave handles 8 nodes; thread = (nl = lane>>4 -> nodes nl, nl+4; cg = lane&15 -> ch 4*cg..4*cg+3)
template <int K>
__global__ __launch_bounds__(256) void lin_attn_kernel(
    const float* __restrict__ in, const float* __restrict__ W,
    const float* __restrict__ a_src, const float* __restrict__ a_dst,
    float* __restrict__ h, float* __restrict__ as_, float* __restrict__ ad_, int N) {
  constexpr int KP = K + 4;
  __shared__ float sW[K * 64];
  __shared__ float sIn[4][8][KP];
  const int t = threadIdx.x;
  const int lane = t & 63, w = t >> 6;
  const int cg = lane & 15, nl = lane >> 4;

  for (int i = t; i < K * 64; i += 256) sW[i] = W[i];

  const int nodeBase = blockIdx.x * 32 + w * 8;
  {
    const int nf4 = 8 * (K / 4);
    const float4* inv4 = (const float4*)(in + (size_t)nodeBase * K);
    for (int i = lane; i < nf4; i += 64) {
      int row = i / (K / 4), j = i % (K / 4);
      if (nodeBase + row < N) {
        float4 v = inv4[i];
        *(float4*)&sIn[w][row][j * 4] = v;
      }
    }
  }
  __syncthreads();

  float acc[2][4] = {{0.f, 0.f, 0.f, 0.f}, {0.f, 0.f, 0.f, 0.f}};
#pragma unroll 8
  for (int k = 0; k < K; k++) {
    float4 wv = *(const float4*)&sW[k * 64 + cg * 4];
    float i0 = sIn[w][nl][k];
    float i1 = sIn[w][nl + 4][k];
    acc[0][0] += i0 * wv.x; acc[0][1] += i0 * wv.y;
    acc[0][2] += i0 * wv.z; acc[0][3] += i0 * wv.w;
    acc[1][0] += i1 * wv.x; acc[1][1] += i1 * wv.y;
    acc[1][2] += i1 * wv.z; acc[1][3] += i1 * wv.w;
  }

  float4 av = *(const float4*)(a_src + cg * 4);
  float4 dv = *(const float4*)(a_dst + cg * 4);
#pragma unroll
  for (int p = 0; p < 2; p++) {
    int n = nodeBase + nl + p * 4;
    if (n < N) {
      float4 hv = make_float4(acc[p][0], acc[p][1], acc[p][2], acc[p][3]);
      *(float4*)(h + (size_t)n * 64 + cg * 4) = hv;
      float ps = acc[p][0] * av.x + acc[p][1] * av.y + acc[p][2] * av.z + acc[p][3] * av.w;
      float pd = acc[p][0] * dv.x + acc[p][1] * dv.y + acc[p][2] * dv.z + acc[p][3] * dv.w;
      for (int m = 1; m < 16; m <<= 1) {
        ps += __shfl_xor(ps, m);
        pd += __shfl_xor(pd, m);
      }
      if (cg == 0) { as_[n] = ps; ad_[n] = pd; }
    }
  }
}

// ---------------- fused softmax + aggregation ----------------
// wave per node, lane = channel. Softmax coefficients computed in-register:
//   pass 1 (lane-parallel over edges): m = max leaky(as_[src]+ad_[n])
//   pass 2: lane j holds num_j = exp(e_j - m); broadcast via shfl; all lanes
//           accumulate acc += num_j * h[src_j][lane]; out = acc/(den+1e-16)
// 4-way unrolled gathers keep 4 independent 256B loads in flight per wave.
__global__ __launch_bounds__(256) void agg_fused_kernel(
    const float* __restrict__ h, const float* __restrict__ as_, const float* __restrict__ ad_,
    const int* __restrict__ csr_src, const int* __restrict__ row_start,
    const float* __restrict__ b, float* __restrict__ out, int N) {
  int t = threadIdx.x;
  int lane = t & 63, w = t >> 6;
  int n = blockIdx.x * 4 + w;
  if (n >= N) return;
  int rs = row_start[n], re = row_start[n + 1];
  float adn = ad_[n];

  // pass 1: running max of leaky-relu'd scores
  float m = -3.4e38f;
  for (int s = rs + lane; s < re; s += 64) {
    int src = csr_src[s];
    float e = as_[src] + adn;
    e = (e > 0.f) ? e : 0.2f * e;
    m = fmaxf(m, e);
  }
#pragma unroll
  for (int k = 1; k < 64; k <<= 1) m = fmaxf(m, __shfl_xor(m, k));

  // pass 2: weighted accumulate
  float acc = 0.f, den = 0.f;
  for (int base = rs; base < re; base += 64) {
    int cnt = re - base;
    if (cnt > 64) cnt = 64;
    int src = 0;
    float num = 0.f;
    if (lane < cnt) {
      src = csr_src[base + lane];
      float e = as_[src] + adn;
      e = (e > 0.f) ? e : 0.2f * e;
      num = __expf(e - m);
      den += num;
    }
    int j = 0;
    for (; j + 4 <= cnt; j += 4) {
      int s0 = __shfl(src, j),     s1 = __shfl(src, j + 1);
      int s2 = __shfl(src, j + 2), s3 = __shfl(src, j + 3);
      float n0 = __shfl(num, j),     n1 = __shfl(num, j + 1);
      float n2 = __shfl(num, j + 2), n3 = __shfl(num, j + 3);
      float h0 = h[(size_t)s0 * 64 + lane];
      float h1 = h[(size_t)s1 * 64 + lane];
      float h2 = h[(size_t)s2 * 64 + lane];
      float h3 = h[(size_t)s3 * 64 + lane];
      acc += n0 * h0;
      acc += n1 * h1;
      acc += n2 * h2;
      acc += n3 * h3;
    }
    for (; j < cnt; j++) {
      int sj = __shfl(src, j);
      float nj = __shfl(num, j);
      acc += nj * h[(size_t)sj * 64 + lane];
    }
  }
#pragma unroll
  for (int k = 1; k < 64; k <<= 1) den += __shfl_xor(den, k);
  float inv = 1.0f / (den + 1e-16f);
  out[(size_t)n * 64 + lane] = fmaxf(acc * inv + b[lane], 0.0f);
}

// ---------------- global max pool + root detection ----------------
__global__ void pool_kernel(const float* __restrict__ h, const int* __restrict__ batch,
                            float* __restrict__ pool, int* __restrict__ root,
                            int N, int chunk) {
  int t = threadIdx.x;
  int lane = t & 63, w = t >> 6;
  int row = blockIdx.x * 4 + w;
  int start = row * chunk;
  if (start >= N) return;
  int end = start + chunk; if (end > N) end = N;
  int cur_g = batch[start];
  if (lane == 0 && (start == 0 || batch[start - 1] != cur_g)) atomicMin(&root[cur_g], start);
  float rm = 0.0f;  // h >= 0 (post-relu), pool init 0
  for (int n = start; n < end; n++) {
    int g = batch[n];
    if (g != cur_g) {
      atomicMax((int*)&pool[(size_t)cur_g * 64 + lane], __float_as_int(rm));
      if (lane == 0) atomicMin(&root[g], n);
      cur_g = g;
      rm = 0.0f;
    }
    rm = fmaxf(rm, h[(size_t)n * 64 + lane]);
  }
  atomicMax((int*)&pool[(size_t)cur_g * 64 + lane], __float_as_int(rm));
}

// ---------------- final fused MLP head (wave per graph) ----------------
__global__ void final_kernel(const float* __restrict__ pool, const int* __restrict__ root,
                             const float* __restrict__ x,
                             const float* __restrict__ lin0_W, const float* __restrict__ lin0_b,
                             const float* __restrict__ linnews_W, const float* __restrict__ linnews_b,
                             const float* __restrict__ lin1_W, const float* __restrict__ lin1_b,
                             float* __restrict__ out, int G, int N) {
  int t = threadIdx.x;
  int lane = t & 63, w = t >> 6;
  int g = blockIdx.x * 4 + w;
  if (g >= G) return;
  float hp = 0.f;
  for (int k = 0; k < 64; k++) hp += pool[(size_t)g * 64 + k] * lin0_W[k * 64 + lane];
  hp = fmaxf(hp + lin0_b[lane], 0.f);
  int r = root[g]; if (r > N - 1) r = N - 1; if (r < 0) r = 0;
  float nw = 0.f;
  for (int k = 0; k < 128; k++) nw += x[(size_t)r * 128 + k] * linnews_W[k * 64 + lane];
  nw = fmaxf(nw + linnews_b[lane], 0.f);
  float p = hp * lin1_W[lane] + nw * lin1_W[64 + lane];
  for (int k = 1; k < 64; k <<= 1) p += __shfl_xor(p, k);
  if (lane == 0) out[g] = 1.0f / (1.0f + __expf(-(p + lin1_b[0])));
}

// ---------------- launch ----------------
extern "C" void kernel_launch(void* const* d_in, const int* in_sizes, int n_in,
                              void* d_out, int out_size, void* d_ws, size_t ws_size,
                              hipStream_t stream) {
  (void)n_in; (void)ws_size;
  const float* x      = (const float*)d_in[0];
  const int*   adj    = (const int*)d_in[1];
  const int*   batch  = (const int*)d_in[2];
  const float* W1     = (const float*)d_in[3];
  const float* asrc1  = (const float*)d_in[4];
  const float* adst1  = (const float*)d_in[5];
  const float* b1     = (const float*)d_in[6];
  const float* W2     = (const float*)d_in[7];
  const float* asrc2  = (const float*)d_in[8];
  const float* adst2  = (const float*)d_in[9];
  const float* b2     = (const float*)d_in[10];
  const float* W3     = (const float*)d_in[11];
  const float* asrc3  = (const float*)d_in[12];
  const float* adst3  = (const float*)d_in[13];
  const float* b3     = (const float*)d_in[14];
  const float* lnW    = (const float*)d_in[15];
  const float* lnb    = (const float*)d_in[16];
  const float* l0W    = (const float*)d_in[17];
  const float* l0b    = (const float*)d_in[18];
  const float* l1W    = (const float*)d_in[19];
  const float* l1b    = (const float*)d_in[20];
  float* outp = (float*)d_out;

  const int N = in_sizes[2];
  const int E = in_sizes[1] / 2;
  const int Etot = E + N;
  const int G = out_size;

  const int* src_e = adj;
  const int* dst_e = adj + E;

  uintptr_t p = (uintptr_t)d_ws;
  auto alloc = [&](size_t bytes) -> void* {
    void* r = (void*)p;
    p += (bytes + 255) & ~(size_t)255;
    return r;
  };
  int*   deg       = (int*)alloc((size_t)N * 4);
  int*   row_start = (int*)alloc((size_t)(N + 1) * 4);
  int*   cursor    = (int*)alloc((size_t)N * 4);
  int*   bsum      = (int*)alloc(1024);
  int*   boff      = (int*)alloc(1024);
  int*   csr_src   = (int*)alloc((size_t)Etot * 4);
  float* h_lin     = (float*)alloc((size_t)N * 64 * 4);
  float* bufA      = (float*)alloc((size_t)N * 64 * 4);
  float* as_       = (float*)alloc((size_t)N * 4);
  float* ad_       = (float*)alloc((size_t)N * 4);
  float* pool      = (float*)alloc((size_t)G * 64 * 4);
  int*   root      = (int*)alloc((size_t)G * 4);

  int initN = (N > G * 64) ? N : G * 64;
  init_kernel<<<dim3((initN + THREADS - 1) / THREADS), dim3(THREADS), 0, stream>>>(deg, pool, root, N, G);

  int egrid = (Etot + THREADS - 1) / THREADS;
  deg_kernel<<<dim3(egrid), dim3(THREADS), 0, stream>>>(dst_e, deg, E, Etot);

  int NB = (N + 1023) / 1024;
  scan1_kernel<<<dim3(NB), dim3(256), 0, stream>>>(deg, row_start + 1, bsum, N);
  scan2_kernel<<<dim3(1), dim3(256), 0, stream>>>(bsum, boff, NB);
  scan3_kernel<<<dim3((N + THREADS - 1) / THREADS), dim3(THREADS), 0, stream>>>(row_start, cursor, boff, N);
  fill_kernel<<<dim3(egrid), dim3(THREADS), 0, stream>>>(src_e, dst_e, cursor, csr_src, E, Etot);

  const int linGrid = (N + 31) / 32;
  const int aggGrid = (N + 3) / 4;

  // layer 1
  lin_attn_kernel<128><<<dim3(linGrid), dim3(256), 0, stream>>>(x, W1, asrc1, adst1, h_lin, as_, ad_, N);
  agg_fused_kernel<<<dim3(aggGrid), dim3(256), 0, stream>>>(h_lin, as_, ad_, csr_src, row_start, b1, bufA, N);
  // layer 2
  lin_attn_kernel<64><<<dim3(linGrid), dim3(256), 0, stream>>>(bufA, W2, asrc2, adst2, h_lin, as_, ad_, N);
  agg_fused_kernel<<<dim3(aggGrid), dim3(256), 0, stream>>>(h_lin, as_, ad_, csr_src, row_start, b2, bufA, N);
  // layer 3
  lin_attn_kernel<64><<<dim3(linGrid), dim3(256), 0, stream>>>(bufA, W3, asrc3, adst3, h_lin, as_, ad_, N);
  agg_fused_kernel<<<dim3(aggGrid), dim3(256), 0, stream>>>(h_lin, as_, ad_, csr_src, row_start, b3, bufA, N);

  // pool + root
  const int ROWS = 2048;
  int chunk = (N + ROWS - 1) / ROWS;
  pool_kernel<<<dim3(ROWS / 4), dim3(256), 0, stream>>>(bufA, batch, pool, root, N, chunk);

  // head
  final_kernel<<<dim3((G + 3) / 4), dim3(256), 0, stream>>>(
      pool, root, x, l0W, l0b, lnW, lnb, l1W, l1b, outp, G, N);
}

// Round 3
// 469.873 us; speedup vs baseline: 1.5144x; 1.1311x over previous
//
#include <hip/hip_runtime.h>
#include <hip/hip_fp16.h>
#include <cstdint>

#define THREADS 256

// ---------------- init ----------------
__global__ void init_kernel(int* deg, float* pool, int* root, int N, int G) {
  int i = blockIdx.x * blockDim.x + threadIdx.x;
  if (i < N) deg[i] = 1;  // self-loop pre-counted
  if (i < G * 64) pool[i] = 0.0f;
  if (i < G) root[i] = 0x7fffffff;
}

// ---------------- CSR build (8 edges/thread for atomic ILP) ----------------
__global__ void deg_kernel(const int* __restrict__ dst_e, int* __restrict__ deg, int E) {
  int i0 = (blockIdx.x * blockDim.x + threadIdx.x) * 8;
  if (i0 >= E) return;
  int d[8];
#pragma unroll
  for (int j = 0; j < 8; j++) d[j] = (i0 + j < E) ? dst_e[i0 + j] : -1;
#pragma unroll
  for (int j = 0; j < 8; j++)
    if (d[j] >= 0) atomicAdd(&deg[d[j]], 1);
}

// block scans 1024 elements (256 threads x 4)
__global__ void scan1_kernel(const int* __restrict__ deg, int* __restrict__ row1,
                             int* __restrict__ bsum, int N) {
  __shared__ int tsum[256];
  int t = threadIdx.x, b = blockIdx.x;
  int base = b * 1024 + t * 4;
  int v[4];
  int run = 0;
  for (int j = 0; j < 4; j++) {
    int idx = base + j;
    int d = (idx < N) ? deg[idx] : 0;
    run += d;
    v[j] = run;
  }
  tsum[t] = run;
  __syncthreads();
  int own = run;
  for (int off = 1; off < 256; off <<= 1) {
    int val = (t >= off) ? tsum[t - off] : 0;
    __syncthreads();
    tsum[t] += val;
    __syncthreads();
  }
  int prefix = tsum[t] - own;
  for (int j = 0; j < 4; j++) {
    int idx = base + j;
    if (idx < N) row1[idx] = prefix + v[j];  // inclusive scan -> row_start[idx+1]
  }
  if (t == 255) bsum[b] = tsum[255];
}

__global__ void scan2_kernel(const int* __restrict__ bsum, int* __restrict__ boff, int NB) {
  __shared__ int s[256];
  int t = threadIdx.x;
  int v = (t < NB) ? bsum[t] : 0;
  s[t] = v;
  __syncthreads();
  int own = v;
  for (int off = 1; off < 256; off <<= 1) {
    int val = (t >= off) ? s[t - off] : 0;
    __syncthreads();
    s[t] += val;
    __syncthreads();
  }
  if (t < NB) boff[t] = s[t] - own;  // exclusive
}

// finalize row_start, init cursor, and drop each node's self-loop into its
// reserved last slot (slot row_start[n+1]-1; real edges fill the rest).
__global__ void scan3_kernel(int* __restrict__ row_start, int* __restrict__ cursor,
                             const int* __restrict__ boff, int* __restrict__ csr_src, int N) {
  int i = blockIdx.x * blockDim.x + threadIdx.x;
  if (i >= N) return;
  int val = row_start[i + 1] + boff[i >> 10];
  row_start[i + 1] = val;
  if (i + 1 < N) cursor[i + 1] = val;
  if (i == 0) { row_start[0] = 0; cursor[0] = 0; }
  csr_src[val - 1] = i;  // self-loop
}

__global__ void fill_kernel(const int* __restrict__ src_e, const int* __restrict__ dst_e,
                            int* __restrict__ cursor, int* __restrict__ csr_src, int E) {
  int i0 = (blockIdx.x * blockDim.x + threadIdx.x) * 8;
  if (i0 >= E) return;
  int s[8], d[8], slot[8];
#pragma unroll
  for (int j = 0; j < 8; j++) {
    int i = i0 + j;
    s[j] = (i < E) ? src_e[i] : -1;
    d[j] = (i < E) ? dst_e[i] : -1;
  }
#pragma unroll
  for (int j = 0; j < 8; j++)
    slot[j] = (d[j] >= 0) ? atomicAdd(&cursor[d[j]], 1) : 0;
#pragma unroll
  for (int j = 0; j < 8; j++)
    if (d[j] >= 0) csr_src[slot[j]] = s[j];
}

// ---------------- linear + attention scalars ----------------
// h2 = packed half2 of (in @ W) [N,32 x half2]; as_/ad_ = h . a_src / a_dst
template <int K>
__global__ __launch_bounds__(256) void lin_attn_kernel(
    const float* __restrict__ in, const float* __restrict__ W,
    const float* __restrict__ a_src, const float* __restrict__ a_dst,
    __half2* __restrict__ h2, float* __restrict__ as_, float* __restrict__ ad_, int N) {
  constexpr int KP = K + 4;
  __shared__ float sW[K * 64];
  __shared__ float sIn[4][8][KP];
  const int t = threadIdx.x;
  const int lane = t & 63, w = t >> 6;
  const int cg = lane & 15, nl = lane >> 4;

  for (int i = t; i < K * 64; i += 256) sW[i] = W[i];

  const int nodeBase = blockIdx.x * 32 + w * 8;
  {
    const int nf4 = 8 * (K / 4);
    const float4* inv4 = (const float4*)(in + (size_t)nodeBase * K);
    for (int i = lane; i < nf4; i += 64) {
      int row = i / (K / 4), j = i % (K / 4);
      if (nodeBase + row < N) {
        float4 v = inv4[i];
        *(float4*)&sIn[w][row][j * 4] = v;
      }
    }
  }
  __syncthreads();

  float acc[2][4] = {{0.f, 0.f, 0.f, 0.f}, {0.f, 0.f, 0.f, 0.f}};
#pragma unroll 8
  for (int k = 0; k < K; k++) {
    float4 wv = *(const float4*)&sW[k * 64 + cg * 4];
    float i0 = sIn[w][nl][k];
    float i1 = sIn[w][nl + 4][k];
    acc[0][0] += i0 * wv.x; acc[0][1] += i0 * wv.y;
    acc[0][2] += i0 * wv.z; acc[0][3] += i0 * wv.w;
    acc[1][0] += i1 * wv.x; acc[1][1] += i1 * wv.y;
    acc[1][2] += i1 * wv.z; acc[1][3] += i1 * wv.w;
  }

  float4 av = *(const float4*)(a_src + cg * 4);
  float4 dv = *(const float4*)(a_dst + cg * 4);
#pragma unroll
  for (int p = 0; p < 2; p++) {
    int n = nodeBase + nl + p * 4;
    if (n < N) {
      __half2 p0 = __floats2half2_rn(acc[p][0], acc[p][1]);
      __half2 p1 = __floats2half2_rn(acc[p][2], acc[p][3]);
      h2[(size_t)n * 32 + cg * 2]     = p0;
      h2[(size_t)n * 32 + cg * 2 + 1] = p1;
      float ps = acc[p][0] * av.x + acc[p][1] * av.y + acc[p][2] * av.z + acc[p][3] * av.w;
      float pd = acc[p][0] * dv.x + acc[p][1] * dv.y + acc[p][2] * dv.z + acc[p][3] * dv.w;
      for (int m = 1; m < 16; m <<= 1) {
        ps += __shfl_xor(ps, m);
        pd += __shfl_xor(pd, m);
      }
      if (cg == 0) { as_[n] = ps; ad_[n] = pd; }
    }
  }
}

// ---------------- fused softmax + aggregation ----------------
// wave per node. lane = (eo = lane>>5: which of 2 edges; c2 = lane&31: channel
// pair). No max subtraction (|e| << 88, exp(e)/sum(exp(e)) identical).
__global__ __launch_bounds__(256) void agg_fused_kernel(
    const __half2* __restrict__ h2, const float* __restrict__ as_, const float* __restrict__ ad_,
    const int* __restrict__ csr_src, const int* __restrict__ row_start,
    const float* __restrict__ b, float* __restrict__ out, int N) {
  int t = threadIdx.x;
  int lane = t & 63, w = t >> 6;
  int n = blockIdx.x * 4 + w;
  if (n >= N) return;
  int rs = row_start[n], re = row_start[n + 1];
  float adn = ad_[n];
  int c2 = lane & 31;
  int eo = lane >> 5;

  float accx = 0.f, accy = 0.f, den = 0.f;
  for (int base = rs; base < re; base += 64) {
    int cnt = re - base;
    if (cnt > 64) cnt = 64;
    int src = 0;
    float num = 0.f;
    if (lane < cnt) {
      src = csr_src[base + lane];
      float e = as_[src] + adn;
      e = (e > 0.f) ? e : 0.2f * e;
      num = __expf(e);
      den += num;
    }
    int j = 0;
    for (; j + 8 <= cnt; j += 8) {
      int j0 = j + eo, j1 = j + 2 + eo, j2 = j + 4 + eo, j3 = j + 6 + eo;
      int s0 = __shfl(src, j0), s1 = __shfl(src, j1);
      int s2 = __shfl(src, j2), s3 = __shfl(src, j3);
      float n0 = __shfl(num, j0), n1 = __shfl(num, j1);
      float n2 = __shfl(num, j2), n3 = __shfl(num, j3);
      float2 h0 = __half22float2(h2[(size_t)s0 * 32 + c2]);
      float2 h1 = __half22float2(h2[(size_t)s1 * 32 + c2]);
      float2 h2v = __half22float2(h2[(size_t)s2 * 32 + c2]);
      float2 h3 = __half22float2(h2[(size_t)s3 * 32 + c2]);
      accx += n0 * h0.x; accy += n0 * h0.y;
      accx += n1 * h1.x; accy += n1 * h1.y;
      accx += n2 * h2v.x; accy += n2 * h2v.y;
      accx += n3 * h3.x; accy += n3 * h3.y;
    }
    for (; j < cnt; j += 2) {
      int jj = j + eo;  // jj==cnt on odd tail -> num there is 0, harmless
      int sj = __shfl(src, jj);
      float nj = __shfl(num, jj);
      float2 hf = __half22float2(h2[(size_t)sj * 32 + c2]);
      accx += nj * hf.x; accy += nj * hf.y;
    }
  }
  // combine the two edge-halves, reduce den across all 64 lanes
  accx += __shfl_xor(accx, 32);
  accy += __shfl_xor(accy, 32);
#pragma unroll
  for (int k = 1; k < 64; k <<= 1) den += __shfl_xor(den, k);
  float inv = 1.0f / (den + 1e-16f);
  if (eo == 0) {
    float2 o;
    o.x = fmaxf(accx * inv + b[c2 * 2], 0.0f);
    o.y = fmaxf(accy * inv + b[c2 * 2 + 1], 0.0f);
    *(float2*)&out[(size_t)n * 64 + c2 * 2] = o;
  }
}

// ---------------- global max pool + root detection ----------------
__global__ void pool_kernel(const float* __restrict__ h, const int* __restrict__ batch,
                            float* __restrict__ pool, int* __restrict__ root,
                            int N, int chunk) {
  int t = threadIdx.x;
  int lane = t & 63, w = t >> 6;
  int row = blockIdx.x * 4 + w;
  int start = row * chunk;
  if (start >= N) return;
  int end = start + chunk; if (end > N) end = N;
  int cur_g = batch[start];
  if (lane == 0 && (start == 0 || batch[start - 1] != cur_g)) atomicMin(&root[cur_g], start);
  float rm = 0.0f;  // h >= 0 (post-relu), pool init 0
  for (int n = start; n < end; n++) {
    int g = batch[n];
    if (g != cur_g) {
      atomicMax((int*)&pool[(size_t)cur_g * 64 + lane], __float_as_int(rm));
      if (lane == 0) atomicMin(&root[g], n);
      cur_g = g;
      rm = 0.0f;
    }
    rm = fmaxf(rm, h[(size_t)n * 64 + lane]);
  }
  atomicMax((int*)&pool[(size_t)cur_g * 64 + lane], __float_as_int(rm));
}

// ---------------- final fused MLP head (wave per graph) ----------------
__global__ void final_kernel(const float* __restrict__ pool, const int* __restrict__ root,
                             const float* __restrict__ x,
                             const float* __restrict__ lin0_W, const float* __restrict__ lin0_b,
                             const float* __restrict__ linnews_W, const float* __restrict__ linnews_b,
                             const float* __restrict__ lin1_W, const float* __restrict__ lin1_b,
                             float* __restrict__ out, int G, int N) {
  int t = threadIdx.x;
  int lane = t & 63, w = t >> 6;
  int g = blockIdx.x * 4 + w;
  if (g >= G) return;
  float hp = 0.f;
  for (int k = 0; k < 64; k++) hp += pool[(size_t)g * 64 + k] * lin0_W[k * 64 + lane];
  hp = fmaxf(hp + lin0_b[lane], 0.f);
  int r = root[g]; if (r > N - 1) r = N - 1; if (r < 0) r = 0;
  float nw = 0.f;
  for (int k = 0; k < 128; k++) nw += x[(size_t)r * 128 + k] * linnews_W[k * 64 + lane];
  nw = fmaxf(nw + linnews_b[lane], 0.f);
  float p = hp * lin1_W[lane] + nw * lin1_W[64 + lane];
  for (int k = 1; k < 64; k <<= 1) p += __shfl_xor(p, k);
  if (lane == 0) out[g] = 1.0f / (1.0f + __expf(-(p + lin1_b[0])));
}

// ---------------- launch ----------------
extern "C" void kernel_launch(void* const* d_in, const int* in_sizes, int n_in,
                              void* d_out, int out_size, void* d_ws, size_t ws_size,
                              hipStream_t stream) {
  (void)n_in; (void)ws_size;
  const float* x      = (const float*)d_in[0];
  const int*   adj    = (const int*)d_in[1];
  const int*   batch  = (const int*)d_in[2];
  const float* W1     = (const float*)d_in[3];
  const float* asrc1  = (const float*)d_in[4];
  const float* adst1  = (const float*)d_in[5];
  const float* b1     = (const float*)d_in[6];
  const float* W2     = (const float*)d_in[7];
  const float* asrc2  = (const float*)d_in[8];
  const float* adst2  = (const float*)d_in[9];
  const float* b2     = (const float*)d_in[10];
  const float* W3     = (const float*)d_in[11];
  const float* asrc3  = (const float*)d_in[12];
  const float* adst3  = (const float*)d_in[13];
  const float* b3     = (const float*)d_in[14];
  const float* lnW    = (const float*)d_in[15];
  const float* lnb    = (const float*)d_in[16];
  const float* l0W    = (const float*)d_in[17];
  const float* l0b    = (const float*)d_in[18];
  const float* l1W    = (const float*)d_in[19];
  const float* l1b    = (const float*)d_in[20];
  float* outp = (float*)d_out;

  const int N = in_sizes[2];
  const int E = in_sizes[1] / 2;
  const int Etot = E + N;
  const int G = out_size;

  const int* src_e = adj;
  const int* dst_e = adj + E;

  uintptr_t p = (uintptr_t)d_ws;
  auto alloc = [&](size_t bytes) -> void* {
    void* r = (void*)p;
    p += (bytes + 255) & ~(size_t)255;
    return r;
  };
  int*     deg       = (int*)alloc((size_t)N * 4);
  int*     row_start = (int*)alloc((size_t)(N + 1) * 4);
  int*     cursor    = (int*)alloc((size_t)N * 4);
  int*     bsum      = (int*)alloc(1024);
  int*     boff      = (int*)alloc(1024);
  int*     csr_src   = (int*)alloc((size_t)Etot * 4);
  __half2* h2        = (__half2*)alloc((size_t)N * 32 * 4);
  float*   bufA      = (float*)alloc((size_t)N * 64 * 4);
  float*   as_       = (float*)alloc((size_t)N * 4);
  float*   ad_       = (float*)alloc((size_t)N * 4);
  float*   pool      = (float*)alloc((size_t)G * 64 * 4);
  int*     root      = (int*)alloc((size_t)G * 4);

  int initN = (N > G * 64) ? N : G * 64;
  init_kernel<<<dim3((initN + THREADS - 1) / THREADS), dim3(THREADS), 0, stream>>>(deg, pool, root, N, G);

  int egrid8 = (E + THREADS * 8 - 1) / (THREADS * 8);
  deg_kernel<<<dim3(egrid8), dim3(THREADS), 0, stream>>>(dst_e, deg, E);

  int NB = (N + 1023) / 1024;
  scan1_kernel<<<dim3(NB), dim3(256), 0, stream>>>(deg, row_start + 1, bsum, N);
  scan2_kernel<<<dim3(1), dim3(256), 0, stream>>>(bsum, boff, NB);
  scan3_kernel<<<dim3((N + THREADS - 1) / THREADS), dim3(THREADS), 0, stream>>>(row_start, cursor, boff, csr_src, N);
  fill_kernel<<<dim3(egrid8), dim3(THREADS), 0, stream>>>(src_e, dst_e, cursor, csr_src, E);

  const int linGrid = (N + 31) / 32;
  const int aggGrid = (N + 3) / 4;

  // layer 1
  lin_attn_kernel<128><<<dim3(linGrid), dim3(256), 0, stream>>>(x, W1, asrc1, adst1, h2, as_, ad_, N);
  agg_fused_kernel<<<dim3(aggGrid), dim3(256), 0, stream>>>(h2, as_, ad_, csr_src, row_start, b1, bufA, N);
  // layer 2
  lin_attn_kernel<64><<<dim3(linGrid), dim3(256), 0, stream>>>(bufA, W2, asrc2, adst2, h2, as_, ad_, N);
  agg_fused_kernel<<<dim3(aggGrid), dim3(256), 0, stream>>>(h2, as_, ad_, csr_src, row_start, b2, bufA, N);
  // layer 3
  lin_attn_kernel<64><<<dim3(linGrid), dim3(256), 0, stream>>>(bufA, W3, asrc3, adst3, h2, as_, ad_, N);
  agg_fused_kernel<<<dim3(aggGrid), dim3(256), 0, stream>>>(h2, as_, ad_, csr_src, row_start, b3, bufA, N);

  // pool + root
  const int ROWS = 2048;
  int chunk = (N + ROWS - 1) / ROWS;
  pool_kernel<<<dim3(ROWS / 4), dim3(256), 0, stream>>>(bufA, batch, pool, root, N, chunk);

  // head
  final_kernel<<<dim3((G + 3) / 4), dim3(256), 0, stream>>>(
      pool, root, x, l0W, l0b, lnW, lnb, l1W, l1b, outp, G, N);
}

// Round 4
// 419.609 us; speedup vs baseline: 1.6958x; 1.1198x over previous
//
#include <hip/hip_runtime.h>
#include <hip/hip_fp16.h>
#include <cstdint>

#define THREADS 256
#define NBLK 64     // blocks for hist/scatter
#define BPAD 512    // padded bucket count (dst>>8; N<=131072)

// ---------------- init ----------------
__global__ void init_kernel(float* pool, int* root, int G) {
  int i = blockIdx.x * blockDim.x + threadIdx.x;
  if (i < G * 64) pool[i] = 0.0f;
  if (i < G) root[i] = 0x7fffffff;
}

// ---------------- CSR build: bucket sort, no global atomics ----------------
// Pass 1: per-block histogram of dst buckets (LDS atomics), transposed store.
__global__ __launch_bounds__(256) void hist_kernel(const int* __restrict__ dst_e,
                                                   int* __restrict__ hist, int E, int chunk) {
  __shared__ int hcnt[BPAD];
  int t = threadIdx.x, blk = blockIdx.x;
  for (int i = t; i < BPAD; i += 256) hcnt[i] = 0;
  __syncthreads();
  int s = blk * chunk, e = s + chunk;
  if (e > E) e = E;
  for (int i = s + t; i < e; i += 256) atomicAdd(&hcnt[dst_e[i] >> 8], 1);
  __syncthreads();
  for (int b = t; b < BPAD; b += 256) hist[b * NBLK + blk] = hcnt[b];
}

// Pass 2: exclusive scan of all BPAD*NBLK histogram entries (one block).
__global__ __launch_bounds__(256) void hscan_kernel(int* __restrict__ hist) {
  __shared__ int part[256];
  const int PER = (BPAD * NBLK) / 256;  // 128
  int t = threadIdx.x;
  int base = t * PER;
  int sum = 0;
  for (int k = 0; k < PER; k++) sum += hist[base + k];
  part[t] = sum;
  __syncthreads();
  int own = sum;
  for (int off = 1; off < 256; off <<= 1) {
    int v = (t >= off) ? part[t - off] : 0;
    __syncthreads();
    part[t] += v;
    __syncthreads();
  }
  int run = part[t] - own;  // exclusive prefix of this thread's range
  for (int k = 0; k < PER; k++) {
    int h = hist[base + k];
    hist[base + k] = run;
    run += h;
  }
}

// Pass 3: scatter edges into bucket-partitioned ebuf (LDS cursors).
__global__ __launch_bounds__(256) void scatter_kernel(const int* __restrict__ src_e,
                                                      const int* __restrict__ dst_e,
                                                      const int* __restrict__ hist,
                                                      int2* __restrict__ ebuf, int E, int chunk) {
  __shared__ int cur[BPAD];
  int t = threadIdx.x, blk = blockIdx.x;
  for (int b = t; b < BPAD; b += 256) cur[b] = hist[b * NBLK + blk];
  __syncthreads();
  int s = blk * chunk, e = s + chunk;
  if (e > E) e = E;
  for (int i = s + t; i < e; i += 256) {
    int d = dst_e[i], sv = src_e[i];
    int slot = atomicAdd(&cur[d >> 8], 1);
    ebuf[slot] = make_int2(sv, d);
  }
}

// Pass 4: per-bucket (256 nodes) CSR finalize: row_start + csr_src (+self-loops).
__global__ __launch_bounds__(256) void build_kernel(const int2* __restrict__ ebuf,
                                                    const int* __restrict__ hist,
                                                    int* __restrict__ row_start,
                                                    int* __restrict__ csr_src,
                                                    int N, int E) {
  __shared__ int counts[256];
  __shared__ int sc[256];
  __shared__ int curw[256];
  int t = threadIdx.x, b = blockIdx.x;
  int nbase = b * 256;
  int ebase = hist[b * NBLK];
  int eend = hist[(b + 1) * NBLK];  // bucket b+1's start (valid: b+1 < BPAD)
  counts[t] = 0;
  __syncthreads();
  int ecount = eend - ebase;
  for (int i = t; i < ecount; i += 256)
    atomicAdd(&counts[ebuf[ebase + i].y - nbase], 1);
  __syncthreads();
  int n = nbase + t;
  int val = (n < N) ? counts[t] + 1 : 0;  // +1 self-loop
  sc[t] = val;
  __syncthreads();
  int own = val;
  for (int off = 1; off < 256; off <<= 1) {
    int v = (t >= off) ? sc[t - off] : 0;
    __syncthreads();
    sc[t] += v;
    __syncthreads();
  }
  int myloc = sc[t] - own;  // exclusive
  int rowb = ebase + nbase;  // prior real edges + prior self-loops
  if (n < N) {
    row_start[n] = rowb + myloc;
    csr_src[rowb + myloc + counts[t]] = n;  // self-loop in last slot of row
    if (n == N - 1) row_start[N] = rowb + myloc + counts[t] + 1;
  }
  curw[t] = rowb + myloc;
  __syncthreads();
  for (int i = t; i < ecount; i += 256) {
    int2 ev = ebuf[ebase + i];
    int pos = atomicAdd(&curw[ev.y - nbase], 1);
    csr_src[pos] = ev.x;
  }
}

// ---------------- linear + attention scalars ----------------
template <int K>
__global__ __launch_bounds__(256) void lin_attn_kernel(
    const float* __restrict__ in, const float* __restrict__ W,
    const float* __restrict__ a_src, const float* __restrict__ a_dst,
    __half2* __restrict__ h2, float* __restrict__ as_, float* __restrict__ ad_, int N) {
  constexpr int KP = K + 4;
  __shared__ float sW[K * 64];
  __shared__ float sIn[4][8][KP];
  const int t = threadIdx.x;
  const int lane = t & 63, w = t >> 6;
  const int cg = lane & 15, nl = lane >> 4;

  for (int i = t; i < K * 64; i += 256) sW[i] = W[i];

  const int nodeBase = blockIdx.x * 32 + w * 8;
  {
    const int nf4 = 8 * (K / 4);
    const float4* inv4 = (const float4*)(in + (size_t)nodeBase * K);
    for (int i = lane; i < nf4; i += 64) {
      int row = i / (K / 4), j = i % (K / 4);
      if (nodeBase + row < N) {
        float4 v = inv4[i];
        *(float4*)&sIn[w][row][j * 4] = v;
      }
    }
  }
  __syncthreads();

  float acc[2][4] = {{0.f, 0.f, 0.f, 0.f}, {0.f, 0.f, 0.f, 0.f}};
#pragma unroll 8
  for (int k = 0; k < K; k++) {
    float4 wv = *(const float4*)&sW[k * 64 + cg * 4];
    float i0 = sIn[w][nl][k];
    float i1 = sIn[w][nl + 4][k];
    acc[0][0] += i0 * wv.x; acc[0][1] += i0 * wv.y;
    acc[0][2] += i0 * wv.z; acc[0][3] += i0 * wv.w;
    acc[1][0] += i1 * wv.x; acc[1][1] += i1 * wv.y;
    acc[1][2] += i1 * wv.z; acc[1][3] += i1 * wv.w;
  }

  float4 av = *(const float4*)(a_src + cg * 4);
  float4 dv = *(const float4*)(a_dst + cg * 4);
#pragma unroll
  for (int p = 0; p < 2; p++) {
    int n = nodeBase + nl + p * 4;
    if (n < N) {
      __half2 p0 = __floats2half2_rn(acc[p][0], acc[p][1]);
      __half2 p1 = __floats2half2_rn(acc[p][2], acc[p][3]);
      h2[(size_t)n * 32 + cg * 2]     = p0;
      h2[(size_t)n * 32 + cg * 2 + 1] = p1;
      float ps = acc[p][0] * av.x + acc[p][1] * av.y + acc[p][2] * av.z + acc[p][3] * av.w;
      float pd = acc[p][0] * dv.x + acc[p][1] * dv.y + acc[p][2] * dv.z + acc[p][3] * dv.w;
      for (int m = 1; m < 16; m <<= 1) {
        ps += __shfl_xor(ps, m);
        pd += __shfl_xor(pd, m);
      }
      if (cg == 0) { as_[n] = ps; ad_[n] = pd; }
    }
  }
}

// ---------------- fused softmax + aggregation ----------------
__global__ __launch_bounds__(256) void agg_fused_kernel(
    const __half2* __restrict__ h2, const float* __restrict__ as_, const float* __restrict__ ad_,
    const int* __restrict__ csr_src, const int* __restrict__ row_start,
    const float* __restrict__ b, float* __restrict__ out, int N) {
  int t = threadIdx.x;
  int lane = t & 63, w = t >> 6;
  int n = blockIdx.x * 4 + w;
  if (n >= N) return;
  int rs = row_start[n], re = row_start[n + 1];
  float adn = ad_[n];
  int c2 = lane & 31;
  int eo = lane >> 5;

  float accx = 0.f, accy = 0.f, den = 0.f;
  for (int base = rs; base < re; base += 64) {
    int cnt = re - base;
    if (cnt > 64) cnt = 64;
    int src = 0;
    float num = 0.f;
    if (lane < cnt) {
      src = csr_src[base + lane];
      float e = as_[src] + adn;
      e = (e > 0.f) ? e : 0.2f * e;
      num = __expf(e);
      den += num;
    }
    int j = 0;
    for (; j + 8 <= cnt; j += 8) {
      int j0 = j + eo, j1 = j + 2 + eo, j2 = j + 4 + eo, j3 = j + 6 + eo;
      int s0 = __shfl(src, j0), s1 = __shfl(src, j1);
      int s2 = __shfl(src, j2), s3 = __shfl(src, j3);
      float n0 = __shfl(num, j0), n1 = __shfl(num, j1);
      float n2 = __shfl(num, j2), n3 = __shfl(num, j3);
      float2 h0 = __half22float2(h2[(size_t)s0 * 32 + c2]);
      float2 h1 = __half22float2(h2[(size_t)s1 * 32 + c2]);
      float2 h2v = __half22float2(h2[(size_t)s2 * 32 + c2]);
      float2 h3 = __half22float2(h2[(size_t)s3 * 32 + c2]);
      accx += n0 * h0.x; accy += n0 * h0.y;
      accx += n1 * h1.x; accy += n1 * h1.y;
      accx += n2 * h2v.x; accy += n2 * h2v.y;
      accx += n3 * h3.x; accy += n3 * h3.y;
    }
    for (; j < cnt; j += 2) {
      int jj = j + eo;
      int sj = __shfl(src, jj);
      float nj = __shfl(num, jj);
      float2 hf = __half22float2(h2[(size_t)sj * 32 + c2]);
      accx += nj * hf.x; accy += nj * hf.y;
    }
  }
  accx += __shfl_xor(accx, 32);
  accy += __shfl_xor(accy, 32);
#pragma unroll
  for (int k = 1; k < 64; k <<= 1) den += __shfl_xor(den, k);
  float inv = 1.0f / (den + 1e-16f);
  if (eo == 0) {
    float2 o;
    o.x = fmaxf(accx * inv + b[c2 * 2], 0.0f);
    o.y = fmaxf(accy * inv + b[c2 * 2 + 1], 0.0f);
    *(float2*)&out[(size_t)n * 64 + c2 * 2] = o;
  }
}

// ---------------- global max pool + root detection ----------------
__global__ void pool_kernel(const float* __restrict__ h, const int* __restrict__ batch,
                            float* __restrict__ pool, int* __restrict__ root,
                            int N, int chunk) {
  int t = threadIdx.x;
  int lane = t & 63, w = t >> 6;
  int row = blockIdx.x * 4 + w;
  int start = row * chunk;
  if (start >= N) return;
  int end = start + chunk; if (end > N) end = N;
  int cur_g = batch[start];
  if (lane == 0 && (start == 0 || batch[start - 1] != cur_g)) atomicMin(&root[cur_g], start);
  float rm = 0.0f;  // h >= 0 (post-relu), pool init 0
  for (int n = start; n < end; n++) {
    int g = batch[n];
    if (g != cur_g) {
      atomicMax((int*)&pool[(size_t)cur_g * 64 + lane], __float_as_int(rm));
      if (lane == 0) atomicMin(&root[g], n);
      cur_g = g;
      rm = 0.0f;
    }
    rm = fmaxf(rm, h[(size_t)n * 64 + lane]);
  }
  atomicMax((int*)&pool[(size_t)cur_g * 64 + lane], __float_as_int(rm));
}

// ---------------- final fused MLP head (wave per graph) ----------------
__global__ void final_kernel(const float* __restrict__ pool, const int* __restrict__ root,
                             const float* __restrict__ x,
                             const float* __restrict__ lin0_W, const float* __restrict__ lin0_b,
                             const float* __restrict__ linnews_W, const float* __restrict__ linnews_b,
                             const float* __restrict__ lin1_W, const float* __restrict__ lin1_b,
                             float* __restrict__ out, int G, int N) {
  int t = threadIdx.x;
  int lane = t & 63, w = t >> 6;
  int g = blockIdx.x * 4 + w;
  if (g >= G) return;
  float hp = 0.f;
  for (int k = 0; k < 64; k++) hp += pool[(size_t)g * 64 + k] * lin0_W[k * 64 + lane];
  hp = fmaxf(hp + lin0_b[lane], 0.f);
  int r = root[g]; if (r > N - 1) r = N - 1; if (r < 0) r = 0;
  float nw = 0.f;
  for (int k = 0; k < 128; k++) nw += x[(size_t)r * 128 + k] * linnews_W[k * 64 + lane];
  nw = fmaxf(nw + linnews_b[lane], 0.f);
  float p = hp * lin1_W[lane] + nw * lin1_W[64 + lane];
  for (int k = 1; k < 64; k <<= 1) p += __shfl_xor(p, k);
  if (lane == 0) out[g] = 1.0f / (1.0f + __expf(-(p + lin1_b[0])));
}

// ---------------- launch ----------------
extern "C" void kernel_launch(void* const* d_in, const int* in_sizes, int n_in,
                              void* d_out, int out_size, void* d_ws, size_t ws_size,
                              hipStream_t stream) {
  (void)n_in; (void)ws_size;
  const float* x      = (const float*)d_in[0];
  const int*   adj    = (const int*)d_in[1];
  const int*   batch  = (const int*)d_in[2];
  const float* W1     = (const float*)d_in[3];
  const float* asrc1  = (const float*)d_in[4];
  const float* adst1  = (const float*)d_in[5];
  const float* b1     = (const float*)d_in[6];
  const float* W2     = (const float*)d_in[7];
  const float* asrc2  = (const float*)d_in[8];
  const float* adst2  = (const float*)d_in[9];
  const float* b2     = (const float*)d_in[10];
  const float* W3     = (const float*)d_in[11];
  const float* asrc3  = (const float*)d_in[12];
  const float* adst3  = (const float*)d_in[13];
  const float* b3     = (const float*)d_in[14];
  const float* lnW    = (const float*)d_in[15];
  const float* lnb    = (const float*)d_in[16];
  const float* l0W    = (const float*)d_in[17];
  const float* l0b    = (const float*)d_in[18];
  const float* l1W    = (const float*)d_in[19];
  const float* l1b    = (const float*)d_in[20];
  float* outp = (float*)d_out;

  const int N = in_sizes[2];
  const int E = in_sizes[1] / 2;
  const int Etot = E + N;
  const int G = out_size;
  const int B = (N + 255) / 256;  // real buckets (<= BPAD)

  const int* src_e = adj;
  const int* dst_e = adj + E;

  uintptr_t p = (uintptr_t)d_ws;
  auto alloc = [&](size_t bytes) -> void* {
    void* r = (void*)p;
    p += (bytes + 255) & ~(size_t)255;
    return r;
  };
  int*     hist      = (int*)alloc((size_t)BPAD * NBLK * 4);
  int*     row_start = (int*)alloc((size_t)(N + 1) * 4);
  int*     csr_src   = (int*)alloc((size_t)Etot * 4);
  int2*    ebuf      = (int2*)alloc((size_t)E * 8);
  __half2* h2        = (__half2*)alloc((size_t)N * 32 * 4);
  float*   bufA      = (float*)alloc((size_t)N * 64 * 4);
  float*   as_       = (float*)alloc((size_t)N * 4);
  float*   ad_       = (float*)alloc((size_t)N * 4);
  float*   pool      = (float*)alloc((size_t)G * 64 * 4);
  int*     root      = (int*)alloc((size_t)G * 4);

  init_kernel<<<dim3((G * 64 + THREADS - 1) / THREADS), dim3(THREADS), 0, stream>>>(pool, root, G);

  int chunk = (E + NBLK - 1) / NBLK;
  hist_kernel<<<dim3(NBLK), dim3(256), 0, stream>>>(dst_e, hist, E, chunk);
  hscan_kernel<<<dim3(1), dim3(256), 0, stream>>>(hist);
  scatter_kernel<<<dim3(NBLK), dim3(256), 0, stream>>>(src_e, dst_e, hist, ebuf, E, chunk);
  build_kernel<<<dim3(B), dim3(256), 0, stream>>>(ebuf, hist, row_start, csr_src, N, E);

  const int linGrid = (N + 31) / 32;
  const int aggGrid = (N + 3) / 4;

  // layer 1
  lin_attn_kernel<128><<<dim3(linGrid), dim3(256), 0, stream>>>(x, W1, asrc1, adst1, h2, as_, ad_, N);
  agg_fused_kernel<<<dim3(aggGrid), dim3(256), 0, stream>>>(h2, as_, ad_, csr_src, row_start, b1, bufA, N);
  // layer 2
  lin_attn_kernel<64><<<dim3(linGrid), dim3(256), 0, stream>>>(bufA, W2, asrc2, adst2, h2, as_, ad_, N);
  agg_fused_kernel<<<dim3(aggGrid), dim3(256), 0, stream>>>(h2, as_, ad_, csr_src, row_start, b2, bufA, N);
  // layer 3
  lin_attn_kernel<64><<<dim3(linGrid), dim3(256), 0, stream>>>(bufA, W3, asrc3, adst3, h2, as_, ad_, N);
  agg_fused_kernel<<<dim3(aggGrid), dim3(256), 0, stream>>>(h2, as_, ad_, csr_src, row_start, b3, bufA, N);

  // pool + root
  const int ROWS = 2048;
  int pchunk = (N + ROWS - 1) / ROWS;
  pool_kernel<<<dim3(ROWS / 4), dim3(256), 0, stream>>>(bufA, batch, pool, root, N, pchunk);

  // head
  final_kernel<<<dim3((G + 3) / 4), dim3(256), 0, stream>>>(
      pool, root, x, l0W, l0b, lnW, lnb, l1W, l1b, outp, G, N);
}